// Round 2
// baseline (743.781 us; speedup 1.0000x reference)
//
#include <hip/hip_runtime.h>
#include <math.h>

// Problem constants (from reference)
#define Bn    256
#define Tn    1024
#define In    64
#define Pn    256
#define En    128
#define NOUTn 64
#define LN_EPS 1e-5f

// softmax factorization constants (TEMP=8):
// z_j ∝ exp((j-2)*frac/4) * exp(-(j-2)^2/8)  (common exp(-frac^2/8) cancels)
#define C1f 0.3606737602222409f     // log2(e)/4
#define K1f 0.8824969025845955f     // exp(-1/8)
#define K2f 0.6065306597126334f     // exp(-4/8)

typedef float f32x2 __attribute__((ext_vector_type(2)));

__device__ __forceinline__ float tanh_fast(float x) {
    float e = __builtin_amdgcn_exp2f(x * 2.88539008177793f);   // e^(2x)
    return 1.0f - 2.0f * __builtin_amdgcn_rcpf(e + 1.0f);
}
__device__ __forceinline__ f32x2 tanh2(f32x2 x) {
    f32x2 e;
    e[0] = __builtin_amdgcn_exp2f(x[0] * 2.88539008177793f);
    e[1] = __builtin_amdgcn_exp2f(x[1] * 2.88539008177793f);
    f32x2 r;
    r[0] = __builtin_amdgcn_rcpf(e[0] + 1.0f);
    r[1] = __builtin_amdgcn_rcpf(e[1] + 1.0f);
    return 1.0f - 2.0f * r;
}

template<int CTRL, int RMASK>
__device__ __forceinline__ float dpp_add(float x) {
    return x + __int_as_float(__builtin_amdgcn_update_dpp(
        0, __float_as_int(x), CTRL, RMASK, 0xF, false));
}
__device__ __forceinline__ void wave_sum64_x3(float& x, float& y, float& z) {
#define LVL(C, R) x = dpp_add<C, R>(x); y = dpp_add<C, R>(y); z = dpp_add<C, R>(z);
    LVL(0x111, 0xF)
    LVL(0x112, 0xF)
    LVL(0x114, 0xF)
    LVL(0x118, 0xF)
    LVL(0x142, 0xA)
    LVL(0x143, 0xC)
#undef LVL
    x = __int_as_float(__builtin_amdgcn_readlane(__float_as_int(x), 63));
    y = __int_as_float(__builtin_amdgcn_readlane(__float_as_int(y), 63));
    z = __int_as_float(__builtin_amdgcn_readlane(__float_as_int(z), 63));
}

// ===========================================================================
// R10: DE-FUSED two-kernel design.
//
// Post-mortem of R9 showed the fused producers (2 waves, 1/SIMD, no TLP) are
// the chunk bottleneck: 128 VMEM loads/chunk with ~2 iters in flight and
// 256 KB/chunk of redundant L1 traffic is latency-bound at 1 wave/SIMD, and
// consumer-side improvements were free (+80 VALU/step cost only +4%).
//
// Kernel 1 (emb_kernel): massively parallel emb = tanh(x @ W_in^T + b_in),
//   4096 blocks x 256 threads (16 blocks/CU -> full TLP latency hiding).
//   Per-thread 4t x 8e tile; accumulation order (i ascending, .x.y.z.w) and
//   tanh_fast are BIT-IDENTICAL to the old fused producer. Output layout
//   [b][g2=t/4][e][t%4] so the scan reads one float4 per channel-pair group.
//   Workspace: 256*256*512*4 = 128 MB in d_ws.
//
// Kernel 2 (scan_kernel): 256 blocks x 64 threads -- ONE wave, no producers,
//   NO barriers in the scan loop. emb read directly from global, prefetched
//   one 4-step group (~1100 cy) ahead -> L2/L3 latency covered. Keeps the
//   R9 branchless dual-candidate jump/walk speculation (identical math).
//   LDS: ring 128 KB + jd 1 KB = 129 KB.
// ===========================================================================

// ---------------------------- Kernel 1 ------------------------------------
__global__ __launch_bounds__(256, 2)
void emb_kernel(const float* __restrict__ x,
                const float* __restrict__ W_in, const float* __restrict__ b_in,
                float* __restrict__ emb) {
    const int b    = blockIdx.x >> 4;        // 0..255
    const int tc   = blockIdx.x & 15;        // 64-t chunk within batch
    const int tid  = threadIdx.x;
    const int tq   = tid >> 4;               // 0..15 : local 4-t group
    const int eidx = tid & 15;               // e = eidx + 16j, j=0..7

    const int t0 = tc * 64 + tq * 4;
    const float4* xr = (const float4*)(x + ((size_t)b * Tn + t0) * In);

    float be[8];
    #pragma unroll
    for (int j = 0; j < 8; ++j) be[j] = b_in[eidx + 16 * j];

    float acc[4][8];
    #pragma unroll
    for (int tt = 0; tt < 4; ++tt)
        #pragma unroll
        for (int j = 0; j < 8; ++j) acc[tt][j] = 0.f;

    #pragma unroll
    for (int i4 = 0; i4 < 16; ++i4) {
        float4 xv[4];
        #pragma unroll
        for (int tt = 0; tt < 4; ++tt) xv[tt] = xr[tt * 16 + i4];
        float4 wf[8];
        #pragma unroll
        for (int j = 0; j < 8; ++j)
            wf[j] = *(const float4*)(W_in + (eidx + 16 * j) * In + i4 * 4);
        #pragma unroll
        for (int tt = 0; tt < 4; ++tt)
            #pragma unroll
            for (int j = 0; j < 8; ++j) {
                acc[tt][j] += xv[tt].x * wf[j].x;
                acc[tt][j] += xv[tt].y * wf[j].y;
                acc[tt][j] += xv[tt].z * wf[j].z;
                acc[tt][j] += xv[tt].w * wf[j].w;
            }
    }

    const int g2 = tc * 16 + tq;             // 0..255 : global 4-t group
    float* og = emb + ((size_t)b * 256 + g2) * 512;
    #pragma unroll
    for (int j = 0; j < 8; ++j) {
        float4 o;
        o.x = tanh_fast(acc[0][j] + be[j]);
        o.y = tanh_fast(acc[1][j] + be[j]);
        o.z = tanh_fast(acc[2][j] + be[j]);
        o.w = tanh_fast(acc[3][j] + be[j]);
        *(float4*)(og + (eidx + 16 * j) * 4) = o;
    }
}

// ---------------------------- Kernel 2 ------------------------------------
#define LDS2_FLOATS (Pn * En + Pn)          // 33024
#define LDS2_BYTES  (LDS2_FLOATS * 4)       // 132096

__global__ __launch_bounds__(64, 1)
void scan_kernel(const float* __restrict__ emb,
                 const float* __restrict__ pointer_init,
                 const float* __restrict__ ln_w, const float* __restrict__ ln_b,
                 const float* __restrict__ jump_dest,
                 const float* __restrict__ Wg,  const float* __restrict__ bg,
                 const float* __restrict__ cs_ptr,
                 const float* __restrict__ Wo,  const float* __restrict__ bo,
                 float* __restrict__ out) {
    extern __shared__ float lds[];
    float* mem = lds;                    // ring: [row][2*l + c]
    float* jd  = lds + Pn * En;          // jump_dest copy

    const int b = blockIdx.x;
    const int l = threadIdx.x;

    float4* m4 = (float4*)mem;
    for (int i = l; i < Pn * En / 4; i += 64) m4[i] = make_float4(0.f, 0.f, 0.f, 0.f);
    for (int i = l; i < Pn; i += 64) jd[i] = jump_dest[i];

    const f32x2 lnw = {ln_w[l], ln_w[l + 64]};
    const f32x2 lnb = {ln_b[l], ln_b[l + 64]};
    const f32x2 wg  = {Wg[l],   Wg[l + 64]};
    const float bgs = bg[0];
    const float cs  = 1.0f / (1.0f + expf(-cs_ptr[0]));
    f32x2 hid = {0.f, 0.f};

    float* myb = mem + 2 * l;

    // ---- dual-candidate pipeline state ----
    float jl = 1.0f;                       // forces JUMP at t=0
    float z0 = 0.f, z1 = 0.f, z2 = 1.f, z3 = 0.f, z4 = 0.f, inv = 1.f;
    float ptrW = 0.f; int baseW = 0; float jtW_pre = 0.f;
    f32x2 wnb0 = {0,0}, wnb1 = {0,0}, wnb2 = {0,0}, wnb3 = {0,0}, wnb4 = {0,0};
    float *wp0 = myb, *wp1 = myb, *wp2 = myb, *wp3 = myb, *wp4 = myb;
    // JUMP candidate: from pointer_init
    float jptr  = pointer_init[b];
    int   jbase = (int)jptr; jbase = jbase > 255 ? 255 : jbase;
    float jz0, jz1, jz2 = 1.f, jz3, jz4, jinv;
    {
        const float frac = jptr - (float)jbase;
        const float r  = __builtin_amdgcn_exp2f(frac * C1f);
        const float ri = __builtin_amdgcn_exp2f(-frac * C1f);
        jz0 = K2f * ri * ri; jz1 = K1f * ri;
        jz3 = K1f * r;       jz4 = K2f * r * r;
        jinv = __builtin_amdgcn_rcpf(((jz0 + jz1) + (jz2 + jz3)) + jz4);
    }
    float *jp0 = mem + (((jbase + 254) & 255) << 7) + 2 * l;
    float *jp1 = mem + (((jbase + 255) & 255) << 7) + 2 * l;
    float *jp2 = mem + ((jbase) << 7) + 2 * l;
    float *jp3 = mem + (((jbase + 1) & 255) << 7) + 2 * l;
    float *jp4 = mem + (((jbase + 2) & 255) << 7) + 2 * l;
    f32x2 jnb0, jnb1, jnb2, jnb3, jnb4;
    float jjt;

    __syncthreads();                       // single wave: cheap; orders LDS init

    jnb0 = *(f32x2*)jp0; jnb1 = *(f32x2*)jp1; jnb2 = *(f32x2*)jp2;
    jnb3 = *(f32x2*)jp3; jnb4 = *(f32x2*)jp4;
    jjt  = jd[jbase];

    // emb group stream: [g2][e][t4], 512 floats per group
    const float* eb = emb + (size_t)b * 256 * 512;
    float4 A0 = *(const float4*)(eb + (size_t)l * 4);
    float4 A1 = *(const float4*)(eb + 256 + (size_t)l * 4);

#define SSTEP(EC0, EC1) {                                                      \
    const bool JMP = jl > 0.0f;                 /* wave-uniform gate */        \
    const f32x2 ctxW = inv  * (((wnb0 * z0  + wnb1 * z1 )                      \
                              + (wnb2 * z2  + wnb3 * z3 )) + wnb4 * z4 );      \
    const f32x2 ctxJ = jinv * (((jnb0 * jz0 + jnb1 * jz1)                      \
                              + (jnb2 * jz2 + jnb3 * jz3)) + jnb4 * jz4);      \
    f32x2 ctx; ctx[0] = JMP ? ctxJ[0] : ctxW[0];                               \
               ctx[1] = JMP ? ctxJ[1] : ctxW[1];                               \
    const float ptr  = JMP ? jptr  : ptrW;                                     \
    const int   base = JMP ? jbase : baseW;                                    \
    z0 = JMP ? jz0 : z0;  z1 = JMP ? jz1 : z1;                                 \
    z3 = JMP ? jz3 : z3;  z4 = JMP ? jz4 : z4;                                 \
    inv = JMP ? jinv : inv;                                                    \
    const f32x2 nb0 = JMP ? jnb0 : wnb0;                                       \
    const f32x2 nb1 = JMP ? jnb1 : wnb1;                                       \
    const f32x2 nb2 = JMP ? jnb2 : wnb2;                                       \
    const f32x2 nb3 = JMP ? jnb3 : wnb3;                                       \
    const f32x2 nb4 = JMP ? jnb4 : wnb4;                                       \
    float* p0 = JMP ? jp0 : wp0;  float* p1 = JMP ? jp1 : wp1;                 \
    float* p2 = JMP ? jp2 : wp2;  float* p3 = JMP ? jp3 : wp3;                 \
    float* p4 = JMP ? jp4 : wp4;                                               \
    const float jt_n = JMP ? jjt : jtW_pre;                                    \
    f32x2 em; em[0] = (EC0); em[1] = (EC1);                                    \
    const f32x2 su = tanh2(em + cs * ctx + hid);                               \
    const f32x2 g  = su * inv;                                                 \
    const f32x2 m0v = nb0 + z0 * g, m1v = nb1 + z1 * g, m2v = nb2 + z2 * g,    \
                m3v = nb3 + z3 * g, m4v = nb4 + z4 * g;                        \
    *(f32x2*)p0 = m0v; *(f32x2*)p1 = m1v; *(f32x2*)p2 = m2v;                   \
    *(f32x2*)p3 = m3v; *(f32x2*)p4 = m4v;                                      \
    baseW = (base + 1) & 255;                                                  \
    ptrW  = ptr + 1.0f; if (ptrW >= 256.0f) ptrW -= 256.0f;                    \
    wnb0 = m1v; wnb1 = m2v; wnb2 = m3v; wnb3 = m4v;                            \
    wp0 = p1; wp1 = p2; wp2 = p3; wp3 = p4;                                    \
    wp4 = mem + (((base + 3) & 255) << 7) + 2 * l;                             \
    wnb4 = *(f32x2*)wp4;                                                       \
    jtW_pre = jd[baseW];                                                       \
    jptr  = jt_n;                                                              \
    jbase = (int)jptr; jbase = jbase > 255 ? 255 : jbase;                      \
    {                                                                          \
        const float frac = jptr - (float)jbase;                                \
        const float r  = __builtin_amdgcn_exp2f(frac * C1f);                   \
        const float ri = __builtin_amdgcn_exp2f(-frac * C1f);                  \
        jz0 = K2f * ri * ri; jz1 = K1f * ri;                                   \
        jz3 = K1f * r;       jz4 = K2f * r * r;                                \
        jinv = __builtin_amdgcn_rcpf(((jz0 + jz1) + (jz2 + jz3)) + jz4);       \
    }                                                                          \
    jp0 = mem + (((jbase + 254) & 255) << 7) + 2 * l;                          \
    jp1 = mem + (((jbase + 255) & 255) << 7) + 2 * l;                          \
    jp2 = mem + ((jbase) << 7) + 2 * l;                                        \
    jp3 = mem + (((jbase + 1) & 255) << 7) + 2 * l;                            \
    jp4 = mem + (((jbase + 2) & 255) << 7) + 2 * l;                            \
    jnb0 = *(f32x2*)jp0; jnb1 = *(f32x2*)jp1; jnb2 = *(f32x2*)jp2;             \
    jnb3 = *(f32x2*)jp3; jnb4 = *(f32x2*)jp4;                                  \
    jjt  = jd[jbase];                                                          \
    float s1 = su[0] + su[1];                                                  \
    const f32x2 sq = su * su;  float s2 = sq[0] + sq[1];                       \
    const f32x2 sg = su * wg;  float s3 = sg[0] + sg[1];                       \
    wave_sum64_x3(s1, s2, s3);                                                 \
    const float mu   = s1 * (1.0f / En);                                       \
    const float var  = s2 * (1.0f / En) - mu * mu;                             \
    const float rstd = __builtin_amdgcn_rsqf(var + LN_EPS);                    \
    hid = (su - mu) * rstd * lnw + lnb;                                        \
    jl  = s3 + bgs;                                                            \
}

    #pragma unroll 1
    for (int g2 = 0; g2 < 256; ++g2) {
        int gn = g2 + 1; if (gn > 255) gn = 255;
        const float* sb = eb + (size_t)gn * 512 + l * 4;
        float4 B0 = *(const float4*)sb;
        float4 B1 = *(const float4*)(sb + 256);
        SSTEP(A0.x, A1.x)
        SSTEP(A0.y, A1.y)
        SSTEP(A0.z, A1.z)
        SSTEP(A0.w, A1.w)
        A0 = B0; A1 = B1;
    }
#undef SSTEP

    // epilogue: logits = hid @ Wo^T + bo
    mem[l] = hid[0]; mem[64 + l] = hid[1];
    __syncthreads();
    const float4* w4 = (const float4*)(Wo + l * En);
    const float4* h4 = (const float4*)mem;
    float a0 = 0.f, a1 = 0.f, a2 = 0.f, a3 = 0.f;
    #pragma unroll
    for (int i = 0; i < En / 4; ++i) {
        float4 wv = w4[i]; float4 hv = h4[i];
        a0 += wv.x * hv.x; a1 += wv.y * hv.y; a2 += wv.z * hv.z; a3 += wv.w * hv.w;
    }
    out[b * NOUTn + l] = (a0 + a1) + (a2 + a3) + bo[l];
}

extern "C" void kernel_launch(void* const* d_in, const int* in_sizes, int n_in,
                              void* d_out, int out_size, void* d_ws, size_t ws_size,
                              hipStream_t stream) {
    const float* x            = (const float*)d_in[0];
    const float* pointer_init = (const float*)d_in[1];
    const float* W_in         = (const float*)d_in[2];
    const float* b_in         = (const float*)d_in[3];
    const float* ln_w         = (const float*)d_in[4];
    const float* ln_b         = (const float*)d_in[5];
    const float* jump_dest    = (const float*)d_in[6];
    const float* Wg           = (const float*)d_in[7];
    const float* bg           = (const float*)d_in[8];
    const float* cs           = (const float*)d_in[9];
    const float* Wo           = (const float*)d_in[10];
    const float* bo           = (const float*)d_in[11];
    float* out = (float*)d_out;
    float* emb = (float*)d_ws;   // 256*256*512*4 = 128 MB

    emb_kernel<<<Bn * 16, 256, 0, stream>>>(x, W_in, b_in, emb);

    (void)hipFuncSetAttribute((const void*)scan_kernel,
                              hipFuncAttributeMaxDynamicSharedMemorySize, LDS2_BYTES);
    scan_kernel<<<Bn, 64, LDS2_BYTES, stream>>>(
        emb, pointer_init, ln_w, ln_b, jump_dest, Wg, bg, cs, Wo, bo, out);
}